// Round 17
// baseline (968.616 us; speedup 1.0000x reference)
//
#include <hip/hip_runtime.h>

typedef __attribute__((ext_vector_type(8))) short short8;
typedef __attribute__((ext_vector_type(4))) float f32x4;
typedef __attribute__((ext_vector_type(4))) unsigned int u32x4;

// ---------- helpers ----------
__device__ __forceinline__ unsigned short f2bu(float x) {
  unsigned int u = __float_as_uint(x);
  u += 0x7fffu + ((u >> 16) & 1u);
  return (unsigned short)(u >> 16);
}
__device__ __forceinline__ unsigned int pk2(float a, float b) {
  return (unsigned int)f2bu(a) | ((unsigned int)f2bu(b) << 16);
}
__device__ __forceinline__ void gload_lds16(const void* g, void* l) {
  __builtin_amdgcn_global_load_lds((const __attribute__((address_space(1))) unsigned int*)g,
                                   (__attribute__((address_space(3))) unsigned int*)l, 16, 0, 0);
}
// coherent DMA (sc0|sc1): reads from the coherence point — proven r8..r16
__device__ __forceinline__ void gload_lds16_coh(const void* g, void* l) {
  __builtin_amdgcn_global_load_lds((const __attribute__((address_space(1))) unsigned int*)g,
                                   (__attribute__((address_space(3))) unsigned int*)l, 16, 0, 17);
}
__device__ __forceinline__ void store16_coh(void* p, u32x4 v) {
  asm volatile("global_store_dwordx4 %0, %1, off sc0 sc1" :: "v"(p), "v"(v) : "memory");
}

// ---------- cast & concat ----------
__global__ void cast_concat_kernel(const float* __restrict__ Mf,
                                   const float* __restrict__ DTf,
                                   const float* __restrict__ Df,
                                   unsigned short* __restrict__ ins) {
  size_t idx = (size_t)blockIdx.x * blockDim.x + threadIdx.x;
  size_t e0 = idx * 8;
  size_t m = e0 >> 10;
  int c = (int)(e0 & 1023);
  const float* src;
  if (c < 256)      src = Mf  + m * 256 + c;
  else if (c < 512) src = DTf + m * 256 + (c - 256);
  else              src = Df  + m * 512 + (c - 512);
  float4 f0 = reinterpret_cast<const float4*>(src)[0];
  float4 f1 = reinterpret_cast<const float4*>(src)[1];
  uint4 o;
  o.x = pk2(f0.x, f0.y); o.y = pk2(f0.z, f0.w);
  o.z = pk2(f1.x, f1.y); o.w = pk2(f1.z, f1.w);
  *reinterpret_cast<uint4*>(ins + e0) = o;
}

__global__ void cast_w_kernel(const float* __restrict__ in, unsigned short* __restrict__ out, int n8) {
  int idx = blockIdx.x * blockDim.x + threadIdx.x;
  if (idx >= n8) return;
  const float* src = in + (size_t)idx * 8;
  float4 f0 = reinterpret_cast<const float4*>(src)[0];
  float4 f1 = reinterpret_cast<const float4*>(src)[1];
  uint4 o;
  o.x = pk2(f0.x, f0.y); o.y = pk2(f0.z, f0.w);
  o.z = pk2(f1.x, f1.y); o.w = pk2(f1.z, f1.w);
  *reinterpret_cast<uint4*>(out + (size_t)idx * 8) = o;
}

// ---------- GEMM: 256x256 tile, BK=64, 4-phase/K-tile deep pipeline (r16) ----------
template <int RELU, typename TOUT>
__global__ __launch_bounds__(512, 2) void gemm256_kernel(
    const unsigned short* __restrict__ A, const unsigned short* __restrict__ Bt,
    TOUT* __restrict__ C, int M, int N, int K) {
  __shared__ unsigned short lds[2][2][16384];
  const int tid = threadIdx.x;
  const int l = tid & 63, w = tid >> 6;
  const int lr = l & 15, lg = l >> 4;
  const int wm = w >> 2, wn = w & 3;
  const int tiles_n = N >> 8;
  const int S = tiles_n << 3;
  const int sgrp = blockIdx.x / S, rr = blockIdx.x % S;
  const int tm = (sgrp << 3) + (rr & 7), tn = rr >> 3;   // XCD A-panel swizzle
  const int bm0 = tm << 8, bn0 = tn << 8;
  const int NT = K >> 6;
  const unsigned short* Ab = A + (size_t)bm0 * K;
  const unsigned short* Bb = Bt + (size_t)bn0 * K;
  const int srow = l >> 3;
  const int scol = ((l & 7) ^ srow) << 3;
  const int swz = lr & 7;

  f32x4 acc[8][4] = {};

#define STG8(SRC, R0, LDSS, KT2)                                              \
  gload_lds16((SRC) + (size_t)((R0) + srow) * K + ((KT2) << 6) + scol,        \
              (LDSS) + (R0) * 64)

#pragma unroll
  for (int t0 = 0; t0 < 2; ++t0) {
    unsigned short* As_ = lds[t0][0];
    unsigned short* Bs_ = lds[t0][1];
    STG8(Ab, (w << 3), As_, t0);
    STG8(Ab, 128 + (w << 3), As_, t0);
    STG8(Ab, 64 + (w << 3), As_, t0);
    STG8(Ab, 192 + (w << 3), As_, t0);
    STG8(Bb, (w << 3), Bs_, t0);
    STG8(Bb, 64 + (w << 3), Bs_, t0);
    STG8(Bb, 128 + (w << 3), Bs_, t0);
    STG8(Bb, 192 + (w << 3), Bs_, t0);
  }
  asm volatile("s_waitcnt vmcnt(8)" ::: "memory");
  __builtin_amdgcn_s_barrier();

  for (int kt = 0; kt < NT; ++kt) {
    const unsigned short* Asd = lds[kt & 1][0];
    const unsigned short* Bsd = lds[kt & 1][1];
    unsigned short* Asn = lds[kt & 1][0];
    unsigned short* Bsn = lds[kt & 1][1];
    const int kt2 = kt + 2;
    const bool dostg = kt2 < NT;

    short8 a[4][2], b[4][2];
#pragma unroll
    for (int i = 0; i < 4; ++i) {
      int row = wm * 128 + i * 16 + lr;
#pragma unroll
      for (int s = 0; s < 2; ++s)
        a[i][s] = *reinterpret_cast<const short8*>(
            Asd + row * 64 + ((((s << 2) + lg) ^ swz) << 3));
    }
#pragma unroll
    for (int ni = 0; ni < 4; ++ni) {
      int row = wn * 64 + ni * 16 + lr;
#pragma unroll
      for (int s = 0; s < 2; ++s)
        b[ni][s] = *reinterpret_cast<const short8*>(
            Bsd + row * 64 + ((((s << 2) + lg) ^ swz) << 3));
    }
    asm volatile("s_waitcnt lgkmcnt(0)" ::: "memory");
    __builtin_amdgcn_sched_barrier(0);
    __builtin_amdgcn_s_setprio(1);
#pragma unroll
    for (int ni = 0; ni < 2; ++ni)
#pragma unroll
      for (int i = 0; i < 4; ++i)
#pragma unroll
        for (int s = 0; s < 2; ++s)
          acc[i][ni] = __builtin_amdgcn_mfma_f32_16x16x32_bf16(a[i][s], b[ni][s], acc[i][ni], 0, 0, 0);
    __builtin_amdgcn_s_setprio(0);
    __builtin_amdgcn_s_barrier();

    if (dostg) {
      STG8(Ab, (w << 3), Asn, kt2);
      STG8(Ab, 128 + (w << 3), Asn, kt2);
      STG8(Bb, (w << 3), Bsn, kt2);
      STG8(Bb, 64 + (w << 3), Bsn, kt2);
    }
    __builtin_amdgcn_s_setprio(1);
#pragma unroll
    for (int ni = 2; ni < 4; ++ni)
#pragma unroll
      for (int i = 0; i < 4; ++i)
#pragma unroll
        for (int s = 0; s < 2; ++s)
          acc[i][ni] = __builtin_amdgcn_mfma_f32_16x16x32_bf16(a[i][s], b[ni][s], acc[i][ni], 0, 0, 0);
    __builtin_amdgcn_s_setprio(0);
    __builtin_amdgcn_s_barrier();

#pragma unroll
    for (int i = 0; i < 4; ++i) {
      int row = wm * 128 + 64 + i * 16 + lr;
#pragma unroll
      for (int s = 0; s < 2; ++s)
        a[i][s] = *reinterpret_cast<const short8*>(
            Asd + row * 64 + ((((s << 2) + lg) ^ swz) << 3));
    }
    if (dostg) {
      STG8(Bb, 128 + (w << 3), Bsn, kt2);
      STG8(Bb, 192 + (w << 3), Bsn, kt2);
    }
    asm volatile("s_waitcnt lgkmcnt(0)" ::: "memory");
    __builtin_amdgcn_sched_barrier(0);
    __builtin_amdgcn_s_setprio(1);
#pragma unroll
    for (int ni = 0; ni < 2; ++ni)
#pragma unroll
      for (int i = 0; i < 4; ++i)
#pragma unroll
        for (int s = 0; s < 2; ++s)
          acc[4 + i][ni] = __builtin_amdgcn_mfma_f32_16x16x32_bf16(a[i][s], b[ni][s], acc[4 + i][ni], 0, 0, 0);
    __builtin_amdgcn_s_setprio(0);
    __builtin_amdgcn_s_barrier();

    if (dostg) {
      STG8(Ab, 64 + (w << 3), Asn, kt2);
      STG8(Ab, 192 + (w << 3), Asn, kt2);
    }
    __builtin_amdgcn_s_setprio(1);
#pragma unroll
    for (int ni = 2; ni < 4; ++ni)
#pragma unroll
      for (int i = 0; i < 4; ++i)
#pragma unroll
        for (int s = 0; s < 2; ++s)
          acc[4 + i][ni] = __builtin_amdgcn_mfma_f32_16x16x32_bf16(a[i][s], b[ni][s], acc[4 + i][ni], 0, 0, 0);
    __builtin_amdgcn_s_setprio(0);
    if (kt + 2 < NT)
      asm volatile("s_waitcnt vmcnt(8)" ::: "memory");
    else
      asm volatile("s_waitcnt vmcnt(0)" ::: "memory");
    __builtin_amdgcn_s_barrier();
  }
#undef STG8

#pragma unroll
  for (int mi = 0; mi < 8; ++mi)
#pragma unroll
    for (int ni = 0; ni < 4; ++ni)
#pragma unroll
      for (int r = 0; r < 4; ++r) {
        int row = bm0 + wm * 128 + mi * 16 + lg * 4 + r;
        int col = bn0 + wn * 64 + ni * 16 + lr;
        float v = acc[mi][ni][r];
        if (RELU) v = fmaxf(v, 0.f);
        if constexpr (sizeof(TOUT) == 2) {
          reinterpret_cast<unsigned short*>(C)[(size_t)row * N + col] = f2bu(v);
        } else {
          C[(size_t)row * N + col] = v;
        }
      }
}

// ---------- xex scrub ----------
__global__ void xscrub_kernel(char* xexb) {
  size_t idx = (size_t)blockIdx.x * blockDim.x + threadIdx.x;
  u32x4 z = {0, 0, 0, 0};
  store16_coh(xexb + idx * 16, z);
}

// ---------- recurrence: r12 structure + calibrated pre-DMA sleep ----------
// The only change vs r16: __builtin_amdgcn_s_sleep(SLEEPN) before the DMA
// issue (t>0) — widens the publish->L3-read window past the sc0sc1 store
// visibility latency, so the first tag check sees fresh data instead of
// paying ~2 retry passes (1.4k cy each).
#define SLEEPN 12

__global__ __launch_bounds__(256)
void recurrence_tf(const float* __restrict__ Whh1,
                   const float* __restrict__ x0f,
                   const float* __restrict__ G,
                   char* xexb,              // [2][16 groups][16KB]
                   float* __restrict__ X, float* __restrict__ Y) {
  __shared__ char smem[163840];
  const int tid = threadIdx.x;
  const int l = tid & 63, wv = tid >> 6;
  const int lr = l & 15, lg = l >> 4;
  const int bid = blockIdx.x;
  const int g = ((bid & 7) << 1) | ((bid >> 3) & 1);
  const int q = bid >> 4;
  const int r0 = g << 4;
  const int jbw = wv << 5;
  char* Wl = smem;
  char* xls0 = smem + 131072;
  char* xls1 = smem + 147456;

  {
    int j = tid >> 1;
    int kc0 = (tid & 1) << 8;
    const float* wr = Whh1 + (size_t)(128 * q + j) * 512 + kc0;
    int sw = (j & 7) << 4;
    for (int kk = 0; kk < 256; kk += 8) {
      float4 f0 = reinterpret_cast<const float4*>(wr + kk)[0];
      float4 f1 = reinterpret_cast<const float4*>(wr + kk)[1];
      uint4 o;
      o.x = pk2(f0.x, f0.y); o.y = pk2(f0.z, f0.w);
      o.z = pk2(f1.x, f1.y); o.w = pk2(f1.z, f1.w);
      *reinterpret_cast<uint4*>(Wl + j * 1024 + ((2 * (kc0 + kk)) ^ sw)) = o;
    }
  }
#pragma unroll
  for (int c = 0; c < 4; ++c) {
    int id = tid + (c << 8);
    int row = id >> 6;
    int kc = (id & 63) << 3;
    int qq = kc >> 7, kp = kc & 127;
    const float* src = x0f + (size_t)(r0 + row) * 512 + kc;
    float4 f0 = reinterpret_cast<const float4*>(src)[0];
    float4 f1 = reinterpret_cast<const float4*>(src)[1];
    uint4 o;
    o.x = pk2(f0.x, f0.y); o.y = pk2(f0.z, f0.w);
    o.z = pk2(f1.x, f1.y); o.w = pk2(f1.z, f1.w);
    *reinterpret_cast<uint4*>(xls0 + qq * 4096 + row * 256 +
                              ((2 * kp) ^ ((row & 7) << 4))) = o;
  }

  float gcur[8], gnxt[8];
#pragma unroll
  for (int jt = 0; jt < 2; ++jt)
#pragma unroll
    for (int r = 0; r < 4; ++r)
      gcur[jt * 4 + r] = G[((size_t)r0 + lg * 4 + r) * 512 + q * 128 + jbw + jt * 16 + lr];
  __syncthreads();

  const int swzR = (lr & 7) << 4;
  int rq[3];
  {
    int n = 0;
    for (int qq = 0; qq < 4; ++qq)
      if (qq != q) rq[n++] = qq;
  }
  float vsave[8];
  short8 arr[12];
  int ep = 1;

  for (int t = 0; t < 256; ++t) {
    char* xc = (t & 1) ? xls1 : xls0;
    const unsigned sh = (unsigned)(((t >> 1) & 1) << 16);
    const u32x4 e = {sh, sh ^ 0x10000u, sh, sh ^ 0x10000u};

    // phase 0: deferred X/Y for t-1, G prefetch for t+1
    if (t) {
      float* Xp = X + ((size_t)(t - 1) * 256 + r0) * 512 + q * 128;
#pragma unroll
      for (int jt = 0; jt < 2; ++jt)
#pragma unroll
        for (int r = 0; r < 4; ++r)
          Xp[(size_t)(lg * 4 + r) * 512 + jbw + jt * 16 + lr] = vsave[jt * 4 + r];
      if (q == 3 && wv == 3 && lr == 15)
#pragma unroll
        for (int r = 0; r < 4; ++r)
          Y[(t - 1) * 256 + r0 + lg * 4 + r] = vsave[4 + r];
    }
    {
      int tn = (t < 255) ? t + 1 : t;
      const float* Gn = G + ((size_t)tn * 256 + r0) * 512 + q * 128;
#pragma unroll
      for (int jt = 0; jt < 2; ++jt)
#pragma unroll
        for (int r = 0; r < 4; ++r)
          gnxt[jt * 4 + r] = Gn[(size_t)(lg * 4 + r) * 512 + jbw + jt * 16 + lr];
    }

    // phase A: own-quarter MFMAs
    f32x4 acc[2] = {};
    {
      short8 ao[4];
#pragma unroll
      for (int kp = 0; kp < 4; ++kp)
        ao[kp] = *reinterpret_cast<const short8*>(
            xc + q * 4096 + lr * 256 + ((kp * 64 + lg * 16) ^ swzR));
#pragma unroll
      for (int jt = 0; jt < 2; ++jt) {
        int jl = jbw + jt * 16 + lr;
        const char* wb = Wl + jl * 1024;
        int swj = (jl & 7) << 4;
#pragma unroll
        for (int kp = 0; kp < 4; ++kp) {
          short8 wf = *reinterpret_cast<const short8*>(
              wb + (((q * 4 + kp) * 64 + lg * 16) ^ swj));
          acc[jt] = __builtin_amdgcn_mfma_f32_16x16x32_bf16(ao[kp], wf, acc[jt], 0, 0, 0);
        }
      }
    }

    // phase B: calibrated sleep -> late DMA, land, tag-verify (retry net)
    unsigned mybad = 0;
#define READCHECK()                                                           \
  {                                                                           \
    mybad = 0;                                                                \
    _Pragma("unroll") for (int m = 0; m < 3; ++m) {                           \
      int qq = rq[m];                                                         \
      _Pragma("unroll") for (int kp = 0; kp < 4; ++kp) {                      \
        short8 f = *reinterpret_cast<const short8*>(                          \
            xc + qq * 4096 + lr * 256 + ((kp * 64 + lg * 16) ^ swzR));        \
        arr[m * 4 + kp] = f;                                                  \
        u32x4 d = __builtin_bit_cast(u32x4, f);                               \
        u32x4 xr = (d ^ e) & 0x10000u;                                        \
        mybad |= xr.x | xr.y | xr.z | xr.w;                                   \
      }                                                                       \
    }                                                                         \
  }
    if (t) {
      __builtin_amdgcn_s_sleep(SLEEPN);   // widen publish->read window
      const char* xsb = xexb + (((t & 1) * 16 + g) * 16384);
#pragma unroll
      for (int m = 0; m < 3; ++m)
        gload_lds16_coh(xsb + rq[m] * 4096 + wv * 1024 + (size_t)l * 16,
                        xc + rq[m] * 4096 + wv * 1024);
      asm volatile("s_waitcnt vmcnt(0)" ::: "memory");
      __builtin_amdgcn_sched_barrier(0);
      __syncthreads();
      READCHECK();
      int* badw = (int*)(xc + q * 4096);
      for (int it = 0; it < 64; ++it) {
        if (__any(mybad != 0)) { if (l == 0) *badw = ep; }
        __syncthreads();
        bool bad = (*badw == ep);
        ++ep;
        if (!bad) break;
#pragma unroll
        for (int m = 0; m < 3; ++m)
          gload_lds16_coh(xsb + rq[m] * 4096 + wv * 1024 + (size_t)l * 16,
                          xc + rq[m] * 4096 + wv * 1024);
        asm volatile("s_waitcnt vmcnt(0)" ::: "memory");
        __builtin_amdgcn_sched_barrier(0);
        __syncthreads();
        READCHECK();
      }
    } else {
      READCHECK();
    }
#undef READCHECK

    // phase C: remote-quarter MFMAs
#pragma unroll
    for (int m = 0; m < 3; ++m) {
      int qq = rq[m];
#pragma unroll
      for (int jt = 0; jt < 2; ++jt) {
        int jl = jbw + jt * 16 + lr;
        const char* wb = Wl + jl * 1024;
        int swj = (jl & 7) << 4;
#pragma unroll
        for (int kp = 0; kp < 4; ++kp) {
          short8 wf = *reinterpret_cast<const short8*>(
              wb + (((qq * 4 + kp) * 64 + lg * 16) ^ swj));
          acc[jt] = __builtin_amdgcn_mfma_f32_16x16x32_bf16(arr[m * 4 + kp], wf, acc[jt], 0, 0, 0);
        }
      }
    }

    // phase D: epilogue
#pragma unroll
    for (int jt = 0; jt < 2; ++jt)
#pragma unroll
      for (int r = 0; r < 4; ++r)
        vsave[jt * 4 + r] = fmaxf(gcur[jt * 4 + r] + acc[jt][r], 0.f);
#pragma unroll
    for (int ee = 0; ee < 8; ++ee) gcur[ee] = gnxt[ee];

    if (t < 255) {
      char* xn = (t & 1) ? xls0 : xls1;
      const unsigned snext = (unsigned)(((t + 1) >> 1) & 1);
#pragma unroll
      for (int jt = 0; jt < 2; ++jt)
#pragma unroll
        for (int r = 0; r < 4; ++r) {
          float v = vsave[jt * 4 + r];
          float vn = __shfl_xor(v, 1);
          if (!(lr & 1)) {
            int i = lg * 4 + r;
            int jc = jbw + jt * 16 + lr;
            unsigned pv = pk2(v, vn);
            pv = (pv & ~0x10000u) | ((snext ^ (unsigned)((jc >> 1) & 1)) << 16);
            *reinterpret_cast<unsigned int*>(
                xn + q * 4096 + i * 256 + ((2 * jc) ^ ((i & 7) << 4))) = pv;
          }
        }
      __syncthreads();
      char* xd = xexb + ((((t + 1) & 1) * 16 + g) * 16384) + q * 4096;
      u32x4 val = *reinterpret_cast<const u32x4*>(xn + q * 4096 + tid * 16);
      store16_coh(xd + tid * 16, val);
    }
  }

  {
    float* Xp = X + ((size_t)255 * 256 + r0) * 512 + q * 128;
#pragma unroll
    for (int jt = 0; jt < 2; ++jt)
#pragma unroll
      for (int r = 0; r < 4; ++r)
        Xp[(size_t)(lg * 4 + r) * 512 + jbw + jt * 16 + lr] = vsave[jt * 4 + r];
    if (q == 3 && wv == 3 && lr == 15)
#pragma unroll
      for (int r = 0; r < 4; ++r)
        Y[255 * 256 + r0 + lg * 4 + r] = vsave[4 + r];
  }
}

// ---------- launch ----------
extern "C" void kernel_launch(void* const* d_in, const int* in_sizes, int n_in,
                              void* d_out, int out_size, void* d_ws, size_t ws_size,
                              hipStream_t stream) {
  const float* x0   = (const float*)d_in[0];
  const float* Mf   = (const float*)d_in[1];
  const float* DTf  = (const float*)d_in[2];
  const float* Df   = (const float*)d_in[3];
  const float* Wih0 = (const float*)d_in[4];
  const float* Wih1 = (const float*)d_in[6];
  const float* Whh1 = (const float*)d_in[7];

  char* ws = (char*)d_ws;
  unsigned short* ins = (unsigned short*)(ws);
  unsigned short* H   = (unsigned short*)(ws + 134217728ULL);
  unsigned short* w0b = (unsigned short*)(ws + 268435456ULL);
  unsigned short* w1b = (unsigned short*)(ws + 270532608ULL);
  char* xex           = ws + 271581184ULL;                     // 512KB: [2][16][16KB]
  float* G = (float*)(ws);   // aliases ins (dead after GEMM1)

  xscrub_kernel<<<128, 256, 0, stream>>>(xex);
  cast_concat_kernel<<<32768, 256, 0, stream>>>(Mf, DTf, Df, ins);
  cast_w_kernel<<<512, 256, 0, stream>>>(Wih0, w0b, 131072);
  cast_w_kernel<<<256, 256, 0, stream>>>(Wih1, w1b, 65536);

  gemm256_kernel<1, unsigned short><<<(65536 / 256) * (1024 / 256), 512, 0, stream>>>(
      ins, w0b, H, 65536, 1024, 1024);
  gemm256_kernel<0, float><<<(65536 / 256) * (512 / 256), 512, 0, stream>>>(
      H, w1b, G, 65536, 512, 1024);

  float* X = (float*)d_out;
  float* Y = X + 33554432;
  recurrence_tf<<<64, 256, 0, stream>>>(Whh1, x0, G, xex, X, Y);
}